// Round 1
// 1756.784 us; speedup vs baseline: 1.2640x; 1.2640x over previous
//
#include <hip/hip_runtime.h>

// LSTM (B=512, T=1024, I=64, H=128) + FC(128->256->1), all fp32.
// Persistent fused kernel: 256 blocks x 512 threads, 1 block/CU, BCHUNK=2
// batch rows per block for the whole T loop (rows independent -> no grid sync).
//
// v2 retile: v1 was LDS-return-bandwidth bound (each LDS element fed exactly
// ONE fma; 96 ds_read_b128/thread/step ~= 3-4k cy/step vs the 1536 cy/step
// FMA floor). Now thread tid = 4*qg + c computes gate rows 4qg..4qg+3 over
// K-chunk c (48 of 192 cols of z=[x|h]): same 384 fma/thread, 4x operand
// reuse -> 24 ds_read_b128/thread/step. Chunk partials are summed with a
// quad DPP butterfly (VALU pipe, no LDS traffic); after the butterfly the
// thread owns exactly gate tid, so activation/gbuf/phase-C match v1.

#define T_STEPS 1024
#define ISZ 64
#define HSZ 128
#define ZSZ (ISZ + HSZ)   // concat operand per row: [x_t | h_{t-1}]
#define G4 512
#define BCHUNK 2
#define NTH 512
#define CLEN 48           // K-chunk length per thread (192/4)
#define NGATE 4           // gate rows per thread

__device__ __forceinline__ float fast_sigmoid(float x) {
    // 1/(1+e^-x): e^x overflow -> 1/(1+inf)=0, underflow -> 1. No NaN.
    return 1.0f / (1.0f + __expf(-x));
}

__device__ __forceinline__ float fast_tanh(float x) {
    // (e^2x - 1)/(e^2x + 1): exact near 0 (no cancellation), clamp avoids inf/inf.
    float xc = fminf(fmaxf(x, -15.0f), 15.0f);
    float u = __expf(2.0f * xc);
    return (u - 1.0f) / (u + 1.0f);
}

// Butterfly sum over the 4 lanes of each quad (lanes 4q..4q+3).
// quad_perm [1,0,3,2] = 0xB1 (xor 1), quad_perm [2,3,0,1] = 0x4E (xor 2).
// Pure VALU (DPP) -> stays off the LDS pipe.
__device__ __forceinline__ float quad_reduce(float v) {
    int t = __builtin_amdgcn_mov_dpp(__float_as_int(v), 0xB1, 0xF, 0xF, true);
    v += __int_as_float(t);
    t = __builtin_amdgcn_mov_dpp(__float_as_int(v), 0x4E, 0xF, 0xF, true);
    v += __int_as_float(t);
    return v;
}

__global__ __launch_bounds__(NTH, 2)  // 2 waves/EU -> VGPR cap 256 (need ~230)
void lstm_fused_kernel(const float* __restrict__ x,
                       const float* __restrict__ W_ih,
                       const float* __restrict__ W_hh,
                       const float* __restrict__ b_ih,
                       const float* __restrict__ b_hh,
                       const float* __restrict__ W1,
                       const float* __restrict__ b1,
                       const float* __restrict__ W2,
                       const float* __restrict__ b2,
                       float* __restrict__ out)
{
    __shared__ __align__(16) float zbuf[BCHUNK][ZSZ];   // [x_t(64) | h(128)] per row
    __shared__ __align__(16) float gbuf[BCHUNK][G4];    // activated gates
    __shared__ float red[BCHUNK][4];

    const int tid = threadIdx.x;
    const int b0 = blockIdx.x * BCHUNK;
    const int c  = tid & 3;     // K-chunk index (0..3)
    const int qg = tid >> 2;    // gate group: gates 4qg..4qg+3

    // ---- per-thread weights: rows 4qg..4qg+3, cols [48c, 48c+48) of [W_ih|W_hh] ----
    // One-time load (L2/L3 cached); per-element address select is init-only cost.
    float wt[NGATE][CLEN];
    #pragma unroll
    for (int i = 0; i < NGATE; ++i) {
        const int g = qg * 4 + i;
        const float* pih = W_ih + (size_t)g * ISZ;
        const float* phh = W_hh + (size_t)g * HSZ;
        #pragma unroll
        for (int k = 0; k < CLEN; ++k) {
            const int col = c * CLEN + k;
            const float* p = (col < ISZ) ? (pih + col) : (phh + (col - ISZ));
            wt[i][k] = *p;
        }
    }
    const float bias = b_ih[tid] + b_hh[tid];   // bias of the gate this thread OWNS (= tid)

    // ---- init: h=0 in LDS, preload x(t=0), c-state in regs of threads 0..127 ----
    if (tid < BCHUNK * HSZ) zbuf[tid >> 7][ISZ + (tid & 127)] = 0.0f;
    if (tid >= 256 && tid < 256 + BCHUNK * ISZ) {
        int l = tid - 256;
        zbuf[l >> 6][l & 63] =
            x[((size_t)(b0 + (l >> 6)) * T_STEPS + 0) * ISZ + (l & 63)];
    }
    float c0 = 0.0f, c1 = 0.0f;
    __syncthreads();

    const int gsel = tid >> 7;  // 0=i 1=f 2=g~ 3=o (PyTorch gate order), wave-uniform

    for (int t = 0; t < T_STEPS; ++t) {
        // issue x(t+1) prefetch early; stored into zbuf x-part during phase C
        float xpre = 0.0f;
        const bool pf = (tid >= 128) && (tid < 256) && (t + 1 < T_STEPS);
        if (pf) {
            int l = tid - 128;
            xpre = x[((size_t)(b0 + (l >> 6)) * T_STEPS + (t + 1)) * ISZ + (l & 63)];
        }

        // ---- phase A: partial gate pre-activations over this thread's K-chunk ----
        float a[NGATE][2];
        #pragma unroll
        for (int i = 0; i < NGATE; ++i) { a[i][0] = 0.0f; a[i][1] = 0.0f; }
        {
            const float4* z0 = reinterpret_cast<const float4*>(zbuf[0]) + c * (CLEN / 4);
            const float4* z1 = reinterpret_cast<const float4*>(zbuf[1]) + c * (CLEN / 4);
            #pragma unroll
            for (int k = 0; k < CLEN / 4; ++k) {
                float4 u = z0[k];
                float4 v = z1[k];
                #pragma unroll
                for (int i = 0; i < NGATE; ++i) {
                    a[i][0] = fmaf(wt[i][4*k  ], u.x, a[i][0]);
                    a[i][0] = fmaf(wt[i][4*k+1], u.y, a[i][0]);
                    a[i][0] = fmaf(wt[i][4*k+2], u.z, a[i][0]);
                    a[i][0] = fmaf(wt[i][4*k+3], u.w, a[i][0]);
                    a[i][1] = fmaf(wt[i][4*k  ], v.x, a[i][1]);
                    a[i][1] = fmaf(wt[i][4*k+1], v.y, a[i][1]);
                    a[i][1] = fmaf(wt[i][4*k+2], v.z, a[i][1]);
                    a[i][1] = fmaf(wt[i][4*k+3], v.w, a[i][1]);
                }
            }
        }

        // ---- sum the 4 K-chunk partials across the quad (DPP butterfly) ----
        #pragma unroll
        for (int i = 0; i < NGATE; ++i) {
            a[i][0] = quad_reduce(a[i][0]);
            a[i][1] = quad_reduce(a[i][1]);
        }
        // all 4 quad lanes now hold all 8 sums; this lane owns gate 4qg+c = tid
        float s0 = (c == 0) ? a[0][0] : (c == 1) ? a[1][0] : (c == 2) ? a[2][0] : a[3][0];
        float s1 = (c == 0) ? a[0][1] : (c == 1) ? a[1][1] : (c == 2) ? a[2][1] : a[3][1];
        s0 += bias;
        s1 += bias;

        // activations (wave-uniform branch: gsel constant per 2-wave group)
        float v0, v1;
        if (gsel == 2) { v0 = fast_tanh(s0);    v1 = fast_tanh(s1);    }
        else           { v0 = fast_sigmoid(s0); v1 = fast_sigmoid(s1); }
        gbuf[0][tid] = v0;
        gbuf[1][tid] = v1;
        __syncthreads();

        // ---- phase C: c/h update (threads 0..127) + x-prefetch store (128..255) ----
        if (tid < HSZ) {
            {
                float ig = gbuf[0][tid];
                float fg = gbuf[0][tid + 128];
                float gv = gbuf[0][tid + 256];
                float og = gbuf[0][tid + 384];
                c0 = fmaf(fg, c0, ig * gv);
                zbuf[0][ISZ + tid] = og * fast_tanh(c0);
            }
            {
                float ig = gbuf[1][tid];
                float fg = gbuf[1][tid + 128];
                float gv = gbuf[1][tid + 256];
                float og = gbuf[1][tid + 384];
                c1 = fmaf(fg, c1, ig * gv);
                zbuf[1][ISZ + tid] = og * fast_tanh(c1);
            }
        } else if (pf) {
            int l = tid - 128;
            zbuf[l >> 6][l & 63] = xpre;   // x-part read next step only (after barrier)
        }
        __syncthreads();
    }

    // ---- FC head: out[b] = W2 . (W1 h + b1) + b2 (fused, per-block) ----
    {
        const int b = tid >> 8;    // threads 0..255 -> row b0, 256..511 -> row b0+1
        const int m = tid & 255;
        const float4* w1r = reinterpret_cast<const float4*>(W1 + (size_t)m * HSZ);
        const float4* hr = reinterpret_cast<const float4*>(zbuf[b] + ISZ);
        float acc = 0.0f;
        #pragma unroll
        for (int k = 0; k < HSZ / 4; ++k) {
            float4 w = w1r[k];
            float4 h = hr[k];
            acc = fmaf(w.x, h.x, acc);
            acc = fmaf(w.y, h.y, acc);
            acc = fmaf(w.z, h.z, acc);
            acc = fmaf(w.w, h.w, acc);
        }
        float z = (acc + b1[m]) * W2[m];
        #pragma unroll
        for (int off = 32; off >= 1; off >>= 1)
            z += __shfl_down(z, off, 64);
        if ((tid & 63) == 0) red[b][(tid >> 6) & 3] = z;
    }
    __syncthreads();
    if (tid == 0)   out[b0]     = red[0][0] + red[0][1] + red[0][2] + red[0][3] + b2[0];
    if (tid == 256) out[b0 + 1] = red[1][0] + red[1][1] + red[1][2] + red[1][3] + b2[0];
}

extern "C" void kernel_launch(void* const* d_in, const int* in_sizes, int n_in,
                              void* d_out, int out_size, void* d_ws, size_t ws_size,
                              hipStream_t stream) {
    const float* x    = (const float*)d_in[0];
    const float* W_ih = (const float*)d_in[1];
    const float* W_hh = (const float*)d_in[2];
    const float* b_ih = (const float*)d_in[3];
    const float* b_hh = (const float*)d_in[4];
    const float* W1   = (const float*)d_in[5];
    const float* b1   = (const float*)d_in[6];
    const float* W2   = (const float*)d_in[7];
    const float* b2   = (const float*)d_in[8];
    float* out = (float*)d_out;

    lstm_fused_kernel<<<dim3(512 / BCHUNK), dim3(NTH), 0, stream>>>(
        x, W_ih, W_hh, b_ih, b_hh, W1, b1, W2, b2, out);
}

// Round 2
// 1583.423 us; speedup vs baseline: 1.4023x; 1.1095x over previous
//
#include <hip/hip_runtime.h>

// LSTM (B=512, T=1024, I=64, H=128) + FC(128->256->1), all fp32.
// Persistent fused kernel: 256 blocks x 1024 threads, 1 block/CU, BCHUNK=2
// batch rows per block for the whole T loop (rows independent -> no grid sync).
//
// v3: v2 was VALU-issue bound with ~2x instruction inflation from AGPR
// spilling (192 weight floats/thread + working set > 124 arch VGPRs at the
// 2-wave/EU 256-combined budget -> v_accvgpr_read per weight use; VALUBusy
// 92% at 4400 cy/step vs a 1920 cy honest demand). Now 1024 threads:
// tid = 8*qg + c owns gate rows 4qg..4qg+3 over a 24-col chunk c of
// z=[x|h]. Weights drop to 96 VGPRs/thread (+~25 working < 128 budget ->
// no spill), per-wave instruction count halves, and 4 waves/SIMD doubles
// latency hiding. Chunk partials are summed with a fold-tree: ds_swizzle
// xor4 (row bit) then DPP quad-perm xor2/xor1 (gate bits); after the fold,
// lane c owns gate 4qg+(c&3) of row c>>2, so the activation/gbuf/phase-C
// structure of v2 carries over.

#define T_STEPS 1024
#define ISZ 64
#define HSZ 128
#define ZSZ (ISZ + HSZ)   // concat operand per row: [x_t | h_{t-1}]
#define G4 512
#define BCHUNK 2
#define NTH 1024
#define CLEN 24           // K-chunk length per thread (192/8)
#define NGATE 4           // gate rows per thread

__device__ __forceinline__ float fast_sigmoid(float x) {
    // 1/(1+e^-x): e^x overflow -> 1/(1+inf)=0, underflow -> 1. No NaN.
    return 1.0f / (1.0f + __expf(-x));
}

__device__ __forceinline__ float fast_tanh(float x) {
    // (e^2x - 1)/(e^2x + 1): exact near 0 (no cancellation), clamp avoids inf/inf.
    float xc = fminf(fmaxf(x, -15.0f), 15.0f);
    float u = __expf(2.0f * xc);
    return (u - 1.0f) / (u + 1.0f);
}

// DPP lane exchanges within quads (VALU pipe, no LDS traffic).
__device__ __forceinline__ float dpp_xor1(float v) {  // quad_perm [1,0,3,2]
    return __int_as_float(__builtin_amdgcn_mov_dpp(__float_as_int(v), 0xB1, 0xF, 0xF, true));
}
__device__ __forceinline__ float dpp_xor2(float v) {  // quad_perm [2,3,0,1]
    return __int_as_float(__builtin_amdgcn_mov_dpp(__float_as_int(v), 0x4E, 0xF, 0xF, true));
}
// lane ^= 4 via ds_swizzle BitMode: offset = (xor<<10)|(or<<5)|and = 0x101F
__device__ __forceinline__ float swz_xor4(float v) {
    return __int_as_float(__builtin_amdgcn_ds_swizzle(__float_as_int(v), 0x101F));
}

__global__ __launch_bounds__(NTH, 4)  // 1024 thr = 4 waves/EU -> 128 VGPR budget (need ~121)
void lstm_fused_kernel(const float* __restrict__ x,
                       const float* __restrict__ W_ih,
                       const float* __restrict__ W_hh,
                       const float* __restrict__ b_ih,
                       const float* __restrict__ b_hh,
                       const float* __restrict__ W1,
                       const float* __restrict__ b1,
                       const float* __restrict__ W2,
                       const float* __restrict__ b2,
                       float* __restrict__ out)
{
    __shared__ __align__(16) float zbuf[BCHUNK][ZSZ];   // [x_t(64) | h(128)] per row
    __shared__ __align__(16) float gbuf[BCHUNK][G4];    // activated gates
    __shared__ float red[BCHUNK][4];

    const int tid = threadIdx.x;
    const int b0 = blockIdx.x * BCHUNK;
    const int c  = tid & 7;     // K-chunk index (0..7)
    const int qg = tid >> 3;    // gate group: gates 4qg..4qg+3  (qg in [0,128))

    // this lane's owned output after the fold: gate 4qg+(c&3), row c>>2
    const int g_own = 4 * qg + (c & 3);
    const bool hi4 = (c & 4) != 0;
    const bool hi2 = (c & 2) != 0;
    const bool hi1 = (c & 1) != 0;

    // ---- per-thread weights: rows 4qg..4qg+3, cols [24c, 24c+24) of [W_ih|W_hh] ----
    // One-time load (L2/L3 cached); per-element address select is init-only cost.
    float wt[NGATE][CLEN];
    #pragma unroll
    for (int i = 0; i < NGATE; ++i) {
        const float* rih = W_ih + (size_t)(4 * qg + i) * ISZ;
        const float* rhh = W_hh + (size_t)(4 * qg + i) * HSZ;
        #pragma unroll
        for (int k = 0; k < CLEN; ++k) {
            const int col = c * CLEN + k;
            wt[i][k] = (col < ISZ) ? rih[col] : rhh[col - ISZ];
        }
    }
    const float bias = b_ih[g_own] + b_hh[g_own];

    // ---- init: h=0 in LDS, preload x(t=0), c-state in regs of threads 0..255 ----
    if (tid < BCHUNK * HSZ) zbuf[tid >> 7][ISZ + (tid & 127)] = 0.0f;
    if (tid >= 256 && tid < 256 + BCHUNK * ISZ) {
        int l = tid - 256;
        zbuf[l >> 6][l & 63] =
            x[((size_t)(b0 + (l >> 6)) * T_STEPS + 0) * ISZ + (l & 63)];
    }
    float cst = 0.0f;           // cell state: thread tid<256 owns (row tid>>7, idx tid&127)
    __syncthreads();

    const int gsel = tid >> 8;  // gate class 0=i 1=f 2=g~ 3=o; wave-uniform (256-thr groups)

    for (int t = 0; t < T_STEPS; ++t) {
        // issue x(t+1) prefetch early (threads 512..639); stored to zbuf in phase C
        float xpre = 0.0f;
        const bool pf = (tid >= 512) && (tid < 640) && (t + 1 < T_STEPS);
        if (pf) {
            int l = tid - 512;
            xpre = x[((size_t)(b0 + (l >> 6)) * T_STEPS + (t + 1)) * ISZ + (l & 63)];
        }

        // ---- phase A: partial pre-activations over this thread's 24-col chunk ----
        float a[NGATE][2];
        #pragma unroll
        for (int i = 0; i < NGATE; ++i) { a[i][0] = 0.0f; a[i][1] = 0.0f; }
        #pragma unroll
        for (int r = 0; r < BCHUNK; ++r) {
            const float4* zr = reinterpret_cast<const float4*>(zbuf[r]) + c * (CLEN / 4);
            #pragma unroll
            for (int k = 0; k < CLEN / 4; ++k) {
                float4 u = zr[k];
                #pragma unroll
                for (int i = 0; i < NGATE; ++i) {
                    a[i][r] = fmaf(wt[i][4*k  ], u.x, a[i][r]);
                    a[i][r] = fmaf(wt[i][4*k+1], u.y, a[i][r]);
                    a[i][r] = fmaf(wt[i][4*k+2], u.z, a[i][r]);
                    a[i][r] = fmaf(wt[i][4*k+3], u.w, a[i][r]);
                }
            }
        }

        // ---- fold-tree over the 8 chunk lanes ----
        // stage xor4: fold the row dimension (lane keeps row c>>2)
        float g4[NGATE];
        #pragma unroll
        for (int i = 0; i < NGATE; ++i) {
            float keep = hi4 ? a[i][1] : a[i][0];
            float send = hi4 ? a[i][0] : a[i][1];
            g4[i] = keep + swz_xor4(send);
        }
        // stage xor2: fold gate bit1 (lane keeps gate-offset bit1 = c bit1)
        float g2[2];
        {
            float k0 = hi2 ? g4[2] : g4[0];
            float s0 = hi2 ? g4[0] : g4[2];
            float k1 = hi2 ? g4[3] : g4[1];
            float s1 = hi2 ? g4[1] : g4[3];
            g2[0] = k0 + dpp_xor2(s0);
            g2[1] = k1 + dpp_xor2(s1);
        }
        // stage xor1: fold gate bit0
        float s;
        {
            float kc = hi1 ? g2[1] : g2[0];
            float sc = hi1 ? g2[0] : g2[1];
            s = kc + dpp_xor1(sc);
        }
        s += bias;   // lane now owns the full pre-activation of gate g_own, row c>>2

        // activation (wave-uniform branch: gsel constant per 4-wave group)
        float v = (gsel == 2) ? fast_tanh(s) : fast_sigmoid(s);
        gbuf[c >> 2][g_own] = v;
        __syncthreads();

        // ---- phase C: c/h update (threads 0..255, one (row,idx) each)
        //      + x-prefetch store (threads 512..639) ----
        if (tid < BCHUNK * HSZ) {
            const int r = tid >> 7;
            const int j = tid & 127;
            float ig = gbuf[r][j];
            float fg = gbuf[r][j + 128];
            float gv = gbuf[r][j + 256];
            float og = gbuf[r][j + 384];
            cst = fmaf(fg, cst, ig * gv);
            zbuf[r][ISZ + j] = og * fast_tanh(cst);
        } else if (pf) {
            int l = tid - 512;
            zbuf[l >> 6][l & 63] = xpre;   // x-part read next step only (after barrier)
        }
        __syncthreads();
    }

    // ---- FC head: out[b] = W2 . (W1 h + b1) + b2 (threads 0..511) ----
    if (tid < 512) {
        const int b = tid >> 8;    // threads 0..255 -> row b0, 256..511 -> row b0+1
        const int m = tid & 255;
        const float4* w1r = reinterpret_cast<const float4*>(W1 + (size_t)m * HSZ);
        const float4* hr = reinterpret_cast<const float4*>(zbuf[b] + ISZ);
        float acc = 0.0f;
        #pragma unroll
        for (int k = 0; k < HSZ / 4; ++k) {
            float4 w = w1r[k];
            float4 h = hr[k];
            acc = fmaf(w.x, h.x, acc);
            acc = fmaf(w.y, h.y, acc);
            acc = fmaf(w.z, h.z, acc);
            acc = fmaf(w.w, h.w, acc);
        }
        float z = (acc + b1[m]) * W2[m];
        #pragma unroll
        for (int off = 32; off >= 1; off >>= 1)
            z += __shfl_down(z, off, 64);
        if ((tid & 63) == 0) red[b][(tid >> 6) & 3] = z;
    }
    __syncthreads();
    if (tid == 0)   out[b0]     = red[0][0] + red[0][1] + red[0][2] + red[0][3] + b2[0];
    if (tid == 256) out[b0 + 1] = red[1][0] + red[1][1] + red[1][2] + red[1][3] + b2[0];
}

extern "C" void kernel_launch(void* const* d_in, const int* in_sizes, int n_in,
                              void* d_out, int out_size, void* d_ws, size_t ws_size,
                              hipStream_t stream) {
    const float* x    = (const float*)d_in[0];
    const float* W_ih = (const float*)d_in[1];
    const float* W_hh = (const float*)d_in[2];
    const float* b_ih = (const float*)d_in[3];
    const float* b_hh = (const float*)d_in[4];
    const float* W1   = (const float*)d_in[5];
    const float* b1   = (const float*)d_in[6];
    const float* W2   = (const float*)d_in[7];
    const float* b2   = (const float*)d_in[8];
    float* out = (float*)d_out;

    lstm_fused_kernel<<<dim3(512 / BCHUNK), dim3(NTH), 0, stream>>>(
        x, W_ih, W_hh, b_ih, b_hh, W1, b1, W2, b2, out);
}